// Round 6
// baseline (178.306 us; speedup 1.0000x reference)
//
#include <hip/hip_runtime.h>

typedef __attribute__((ext_vector_type(8))) short short8;
typedef __attribute__((ext_vector_type(4))) float floatx4;
typedef unsigned int uint;
typedef unsigned short ushort;
typedef __attribute__((ext_vector_type(4))) uint uintx4;

#define NTOK   8192
#define DIN    1024
#define DOUT   1024
#define NJ     96        // 84 decision nodes (12 trees x 7) + 12 gates
#define TOKPB  16        // tokens per block -> 512 blocks
#define DSTR   97        // decis LDS row stride (f32)
#define SSTR   85        // sdec LDS row stride (f32)
#define RSTR   104       // routed LDS tile row stride (bf16)
#define LOT_H  (DOUT * NJ)

static __device__ inline ushort f2b(float f) {
    uint u = __builtin_bit_cast(uint, f);
    u = u + 0x7fffu + ((u >> 16) & 1u);   // RNE
    return (ushort)(u >> 16);
}
static __device__ inline uint pack2(float a, float b) {
    return (uint)f2b(a) | ((uint)f2b(b) << 16);
}

// ---------------------------------------------------------------------------
// k_prep: f32 -> bf16.  lo [3][96][1024] -> lot [3][1024][96] (transposed);
// dw[84][1024] ++ gw[12][1024] -> wcat[96][1024].
// ---------------------------------------------------------------------------
__global__ __launch_bounds__(256) void k_prep(const float* __restrict__ lo,
                                              const float* __restrict__ dw,
                                              const float* __restrict__ gw,
                                              ushort* __restrict__ lot,
                                              ushort* __restrict__ wcat) {
    int i = blockIdx.x * 256 + threadIdx.x;
    if (i < 3 * LOT_H) {
        int h = i / LOT_H;
        int rem = i - h * LOT_H;
        int k = rem >> 10;
        int d = rem & 1023;
        lot[h * LOT_H + d * NJ + k] = f2b(lo[i]);
    } else {
        int j = i - 3 * LOT_H;
        int r = j >> 10, c = j & 1023;
        float v = (r < 84) ? dw[r * DIN + c] : gw[(r - 84) * DIN + c];
        wcat[j] = f2b(v);
    }
}

// ---------------------------------------------------------------------------
// k_fused: 16 tokens/block, 512 blocks, 512 THREADS (8 waves) = 16 waves/CU.
// R5 counters showed 62.8us latency-bound (Occ 20%, VALU 12.6%, HBM 32%):
// 8 waves/CU could not hide L2 latency.  This version doubles waves/CU.
//   phase 1 (waves 0-5, one 16-wide N-tile each): decisions+gates GEMM
//     (M=16, N=96, K=1024), barrier-free; A-frags per-lane from global x
//     (f32->bf16 pack in regs), B-frags from wcat (L2-hot).
//   early B-prefetch: phase-2 groups 0-1 issued by ALL waves before the
//     epilogue barriers (independent of rt) -> latency overlaps epilogue.
//   epilogue: acc -> decis -> sigmoid -> routing -> rt tile (3 barriers).
//   phase 2: out GEMM (M=16, N=3072, K=96); 384 cols/wave (24 tiles,
//     12 groups of 2), triple-buffered B prefetch distance 2; loads issued
//     before previous group's stores; non-temporal f32 stores.
// ---------------------------------------------------------------------------
__global__ __launch_bounds__(512, 4) void k_fused(
    const float* __restrict__ x,     // [8192][1024] f32
    const ushort* __restrict__ wcat, // [96][1024] bf16
    const float* __restrict__ db,    // [84]
    const float* __restrict__ ntl,   // [84]
    const float* __restrict__ gb,    // [12]
    const int*   __restrict__ pi,    // [8][3]
    const float* __restrict__ pd,    // [8][3]
    const ushort* __restrict__ lot,  // [3][1024][96] bf16
    float* __restrict__ out)         // [3][8192][1024] f32
{
    __shared__ float decis[TOKPB * DSTR];
    __shared__ float sdecs[TOKPB * SSTR];
    __shared__ __attribute__((aligned(16))) ushort rt[TOKPB][RSTR];
    __shared__ float invt[84];
    __shared__ float biasf[96];
    __shared__ int   pis[24];
    __shared__ float pds[24];

    const int tid = threadIdx.x;
    const int tb  = blockIdx.x * TOKPB;

    if (tid < 84) {
        float z = ntl[tid] + 0.5413f;
        float sp = (z > 20.0f) ? z : log1pf(__expf(z));   // softplus
        invt[tid]  = 1.0f / sp;
        biasf[tid] = db[tid];
    } else if (tid < 96) {
        biasf[tid] = gb[tid - 84];
    } else if (tid < 120) {
        pis[tid - 96] = pi[tid - 96];
    } else if (tid < 144) {
        pds[tid - 120] = pd[tid - 120];
    }

    const int wave = tid >> 6, lane = tid & 63;
    const int lrow = lane & 15, quad = lane >> 4;

    // ---------------- phase 1: waves 0-5 own N-tiles 0-5 ----------------
    floatx4 acc0 = (floatx4)(0.0f);
    const int ntc = (wave < 6) ? wave : 0;   // clamp: waves 6,7 never use it
    const float*  xr = x    + (size_t)(tb + lrow) * DIN + quad * 8;
    const ushort* w0 = wcat + (size_t)(ntc * 16 + lrow) * DIN + quad * 8;

    if (wave < 6) {
#pragma unroll
        for (int kc = 0; kc < 8; ++kc) {
            short8 a[4];
#pragma unroll
            for (int kt = 0; kt < 4; ++kt) {
                floatx4 u = *(const floatx4*)(xr + kc * 128 + kt * 32);
                floatx4 v = *(const floatx4*)(xr + kc * 128 + kt * 32 + 4);
                union { short8 s; uint w[4]; } pk;
                pk.w[0] = pack2(u[0], u[1]);
                pk.w[1] = pack2(u[2], u[3]);
                pk.w[2] = pack2(v[0], v[1]);
                pk.w[3] = pack2(v[2], v[3]);
                a[kt] = pk.s;
            }
#pragma unroll
            for (int kt = 0; kt < 4; ++kt) {
                short8 b0 = *(const short8*)(w0 + kc * 128 + kt * 32);
                acc0 = __builtin_amdgcn_mfma_f32_16x16x32_bf16(a[kt], b0, acc0, 0, 0, 0);
            }
        }
    }

    // ---------------- early phase-2 B prefetch (all waves) --------------
    // 384 cols per wave; tiles (G*2+q)*16 within the wave's span.
    short8 bb[3][6];
#define LOADB(B, G) do { \
    _Pragma("unroll") for (int q_ = 0; q_ < 2; ++q_) { \
        int c_ = wave * 384 + ((G) * 2 + q_) * 16; \
        int h_ = c_ >> 10; \
        int d_ = (c_ & 1023) + lrow; \
        const ushort* bp_ = lot + (size_t)h_ * LOT_H + (size_t)d_ * NJ + quad * 8; \
        _Pragma("unroll") for (int kk_ = 0; kk_ < 3; ++kk_) \
            bb[B][q_ * 3 + kk_] = *(const short8*)(bp_ + kk_ * 32); \
    } } while (0)

    LOADB(0, 0);
    LOADB(1, 1);

    // ---------------- epilogue: routing ---------------------------------
    // C/D: col = lane&15 (j within 16-tile), row = quad*4+reg (token)
    if (wave < 6) {
#pragma unroll
        for (int r = 0; r < 4; ++r)
            decis[(quad * 4 + r) * DSTR + wave * 16 + lrow] = acc0[r];
    }
    __syncthreads();

    // stage 1: sigmoid over 16 tokens x 84 nodes = 1344 (3 x 512)
#pragma unroll
    for (int i = 0; i < 3; ++i) {
        int idx = tid + 512 * i;
        if (idx < TOKPB * 84) {
            int tk = idx / 84, nd = idx - tk * 84;
            float dv = (decis[tk * DSTR + nd] + biasf[nd]) * invt[nd];
            sdecs[tk * SSTR + nd] = 1.0f / (1.0f + __expf(-dv));
        }
    }
    __syncthreads();

    // stage 2: 512 threads = 16 tokens x 8 leaves x 4 tree-quarters
    {
        const int tk = tid >> 5, l = (tid >> 2) & 7, th = tid & 3;
        float g[12], gm = -1e30f;
#pragma unroll
        for (int tt = 0; tt < 12; ++tt) {
            g[tt] = decis[tk * DSTR + 84 + tt] + biasf[84 + tt];
            gm = fmaxf(gm, g[tt]);
        }
        float gs = 0.0f;
#pragma unroll
        for (int tt = 0; tt < 12; ++tt) { g[tt] = __expf(g[tt] - gm); gs += g[tt]; }
        float ginv = 1.0f / gs;

        const int   n0 = pis[l * 3 + 0], n1 = pis[l * 3 + 1], n2 = pis[l * 3 + 2];
        const float d0 = pds[l * 3 + 0], d1 = pds[l * 3 + 1], d2 = pds[l * 3 + 2];
        const float* sd = sdecs + tk * SSTR;
        const int t0 = th * 3;
#pragma unroll
        for (int t = 0; t < 3; ++t) {
            int tt = t0 + t;
            float s0 = sd[tt * 7 + n0], s1 = sd[tt * 7 + n1], s2 = sd[tt * 7 + n2];
            float pb = g[tt] * ginv
                     * (d0 * s0 + (1.0f - d0) * (1.0f - s0))
                     * (d1 * s1 + (1.0f - d1) * (1.0f - s1))
                     * (d2 * s2 + (1.0f - d2) * (1.0f - s2));
            rt[tk][tt * 8 + l] = f2b(pb);
        }
    }
    __syncthreads();

    // ---------------- phase 2: out GEMM ---------------------------------
    // Each wave: 384 cols = 24 16-col tiles = 12 groups of 2.
    // Triple-buffered B prefetch (distance 2 ~ L2 latency); group g+2
    // loads issued BEFORE group g's stores.  Fully unrolled => all
    // buffer indices static (no scratch).
    {
        short8 a[3];
#pragma unroll
        for (int kk = 0; kk < 3; ++kk)
            a[kk] = *(const short8*)(&rt[lrow][quad * 8 + kk * 32]);

#pragma unroll
        for (int g = 0; g < 12; ++g) {
            const int cur = g % 3;
            if (g < 10) LOADB((g + 2) % 3, g + 2);
#pragma unroll
            for (int q = 0; q < 2; ++q) {
                floatx4 c0 = (floatx4)(0.0f);
#pragma unroll
                for (int kk = 0; kk < 3; ++kk)
                    c0 = __builtin_amdgcn_mfma_f32_16x16x32_bf16(a[kk], bb[cur][q * 3 + kk], c0, 0, 0, 0);
                int c = wave * 384 + (g * 2 + q) * 16;
                int h = c >> 10;
                int d = (c & 1023) + lrow;
                float* ob = out + ((size_t)h * NTOK + tb) * DOUT + d;
#pragma unroll
                for (int r = 0; r < 4; ++r)
                    __builtin_nontemporal_store(c0[r], ob + (size_t)(quad * 4 + r) * DOUT);
            }
        }
#undef LOADB
    }
}

// ---------------------------------------------------------------------------
extern "C" void kernel_launch(void* const* d_in, const int* in_sizes, int n_in,
                              void* d_out, int out_size, void* d_ws, size_t ws_size,
                              hipStream_t stream) {
    const float* x   = (const float*)d_in[0];
    const float* dw  = (const float*)d_in[1];
    const float* db  = (const float*)d_in[2];
    const float* ntl = (const float*)d_in[3];
    const float* gw  = (const float*)d_in[4];
    const float* gb  = (const float*)d_in[5];
    const float* lo  = (const float*)d_in[6];
    const int*   pi  = (const int*)d_in[7];
    const float* pd  = (const float*)d_in[8];
    float* out = (float*)d_out;

    ushort* lot  = (ushort*)d_ws;                 // 3*98304*2 = 0.59 MB
    ushort* wcat = lot + (size_t)3 * LOT_H;       // 96*1024*2 = 0.20 MB

    k_prep<<<dim3((3 * LOT_H + NJ * DIN) / 256), dim3(256), 0, stream>>>(lo, dw, gw, lot, wcat);
    k_fused<<<dim3(NTOK / TOKPB), dim3(512), 0, stream>>>(x, wcat, db, ntl, gb, pi, pd, lot, out);
}

// Round 7
// 177.880 us; speedup vs baseline: 1.0024x; 1.0024x over previous
//
#include <hip/hip_runtime.h>

typedef __attribute__((ext_vector_type(8))) short short8;
typedef __attribute__((ext_vector_type(4))) float floatx4;
typedef unsigned int uint;
typedef unsigned short ushort;
typedef __attribute__((ext_vector_type(4))) uint uintx4;

#define NTOK   8192
#define DIN    1024
#define DOUT   1024
#define NJ     96        // 84 decision nodes (12 trees x 7) + 12 gates
#define TOKPB  16        // tokens per block -> 512 blocks
#define DSTR   97        // decis LDS row stride (f32)
#define SSTR   85        // sdec LDS row stride (f32)
#define RSTR   104       // routed LDS tile row stride (bf16)
#define STG    72        // phase-2 staging row stride (f32): 288B, 16B-aligned,
                         // 2-way max conflict on b128 reads
#define LOT_H  (DOUT * NJ)

static __device__ inline ushort f2b(float f) {
    uint u = __builtin_bit_cast(uint, f);
    u = u + 0x7fffu + ((u >> 16) & 1u);   // RNE
    return (ushort)(u >> 16);
}
static __device__ inline uint pack2(float a, float b) {
    return (uint)f2b(a) | ((uint)f2b(b) << 16);
}

// ---------------------------------------------------------------------------
// k_prep: f32 -> bf16.  lo [3][96][1024] -> lot [3][1024][96] (transposed);
// dw[84][1024] ++ gw[12][1024] -> wcat[96][1024].
// ---------------------------------------------------------------------------
__global__ __launch_bounds__(256) void k_prep(const float* __restrict__ lo,
                                              const float* __restrict__ dw,
                                              const float* __restrict__ gw,
                                              ushort* __restrict__ lot,
                                              ushort* __restrict__ wcat) {
    int i = blockIdx.x * 256 + threadIdx.x;
    if (i < 3 * LOT_H) {
        int h = i / LOT_H;
        int rem = i - h * LOT_H;
        int k = rem >> 10;
        int d = rem & 1023;
        lot[h * LOT_H + d * NJ + k] = f2b(lo[i]);
    } else {
        int j = i - 3 * LOT_H;
        int r = j >> 10, c = j & 1023;
        float v = (r < 84) ? dw[r * DIN + c] : gw[(r - 84) * DIN + c];
        wcat[j] = f2b(v);
    }
}

// ---------------------------------------------------------------------------
// k_fused: 16 tokens/block, 512 blocks, 512 threads (8 waves).
// R6 counters: WRITE_SIZE 129MB (1.28x amplified), write drain ~1.9 TB/s
// vs fillBuffer's 6.4 TB/s -> scalar partial-line NT stores were the
// serializer.  This version:
//   phase 1 (waves 0-5): decisions+gates GEMM, barrier-free, A-frags
//     per-lane from global x (f32->bf16 pack), B-frags from wcat (L2-hot).
//   epilogue: acc -> decis -> sigmoid -> routing -> rt tile (3 barriers).
//   phase 2: out GEMM (M=16, N=3072, K=96) in 64-col groups; acc staged
//     through a wave-private LDS buffer (wave-synchronous, no barrier),
//     then PLAIN float4 stores where each instruction writes 8 FULL
//     128-B lines (8 rows x 32 floats) -- the proven-fast fill pattern.
// ---------------------------------------------------------------------------
__global__ __launch_bounds__(512, 4) void k_fused(
    const float* __restrict__ x,     // [8192][1024] f32
    const ushort* __restrict__ wcat, // [96][1024] bf16
    const float* __restrict__ db,    // [84]
    const float* __restrict__ ntl,   // [84]
    const float* __restrict__ gb,    // [12]
    const int*   __restrict__ pi,    // [8][3]
    const float* __restrict__ pd,    // [8][3]
    const ushort* __restrict__ lot,  // [3][1024][96] bf16
    float* __restrict__ out)         // [3][8192][1024] f32
{
    __shared__ float decis[TOKPB * DSTR];
    __shared__ float sdecs[TOKPB * SSTR];
    __shared__ __attribute__((aligned(16))) ushort rt[TOKPB][RSTR];
    __shared__ __attribute__((aligned(16))) float stg[8][TOKPB * STG];
    __shared__ float invt[84];
    __shared__ float biasf[96];
    __shared__ int   pis[24];
    __shared__ float pds[24];

    const int tid = threadIdx.x;
    const int tb  = blockIdx.x * TOKPB;

    if (tid < 84) {
        float z = ntl[tid] + 0.5413f;
        float sp = (z > 20.0f) ? z : log1pf(__expf(z));   // softplus
        invt[tid]  = 1.0f / sp;
        biasf[tid] = db[tid];
    } else if (tid < 96) {
        biasf[tid] = gb[tid - 84];
    } else if (tid < 120) {
        pis[tid - 96] = pi[tid - 96];
    } else if (tid < 144) {
        pds[tid - 120] = pd[tid - 120];
    }

    const int wave = tid >> 6, lane = tid & 63;
    const int lrow = lane & 15, quad = lane >> 4;

    // ---------------- phase 1: waves 0-5 own N-tiles 0-5 ----------------
    floatx4 acc0 = (floatx4)(0.0f);
    const int ntc = (wave < 6) ? wave : 0;   // clamp: waves 6,7 never use it
    const float*  xr = x    + (size_t)(tb + lrow) * DIN + quad * 8;
    const ushort* w0 = wcat + (size_t)(ntc * 16 + lrow) * DIN + quad * 8;

    if (wave < 6) {
#pragma unroll
        for (int kc = 0; kc < 8; ++kc) {
            short8 a[4];
#pragma unroll
            for (int kt = 0; kt < 4; ++kt) {
                floatx4 u = *(const floatx4*)(xr + kc * 128 + kt * 32);
                floatx4 v = *(const floatx4*)(xr + kc * 128 + kt * 32 + 4);
                union { short8 s; uint w[4]; } pk;
                pk.w[0] = pack2(u[0], u[1]);
                pk.w[1] = pack2(u[2], u[3]);
                pk.w[2] = pack2(v[0], v[1]);
                pk.w[3] = pack2(v[2], v[3]);
                a[kt] = pk.s;
            }
#pragma unroll
            for (int kt = 0; kt < 4; ++kt) {
                short8 b0 = *(const short8*)(w0 + kc * 128 + kt * 32);
                acc0 = __builtin_amdgcn_mfma_f32_16x16x32_bf16(a[kt], b0, acc0, 0, 0, 0);
            }
        }
    }

    // ---------------- epilogue: routing ---------------------------------
    // C/D: col = lane&15 (j within 16-tile), row = quad*4+reg (token)
    if (wave < 6) {
#pragma unroll
        for (int r = 0; r < 4; ++r)
            decis[(quad * 4 + r) * DSTR + wave * 16 + lrow] = acc0[r];
    }
    __syncthreads();

    // stage 1: sigmoid over 16 tokens x 84 nodes = 1344 (3 x 512)
#pragma unroll
    for (int i = 0; i < 3; ++i) {
        int idx = tid + 512 * i;
        if (idx < TOKPB * 84) {
            int tk = idx / 84, nd = idx - tk * 84;
            float dv = (decis[tk * DSTR + nd] + biasf[nd]) * invt[nd];
            sdecs[tk * SSTR + nd] = 1.0f / (1.0f + __expf(-dv));
        }
    }
    __syncthreads();

    // stage 2: 512 threads = 16 tokens x 8 leaves x 4 tree-quarters
    {
        const int tk = tid >> 5, l = (tid >> 2) & 7, th = tid & 3;
        float g[12], gm = -1e30f;
#pragma unroll
        for (int tt = 0; tt < 12; ++tt) {
            g[tt] = decis[tk * DSTR + 84 + tt] + biasf[84 + tt];
            gm = fmaxf(gm, g[tt]);
        }
        float gs = 0.0f;
#pragma unroll
        for (int tt = 0; tt < 12; ++tt) { g[tt] = __expf(g[tt] - gm); gs += g[tt]; }
        float ginv = 1.0f / gs;

        const int   n0 = pis[l * 3 + 0], n1 = pis[l * 3 + 1], n2 = pis[l * 3 + 2];
        const float d0 = pds[l * 3 + 0], d1 = pds[l * 3 + 1], d2 = pds[l * 3 + 2];
        const float* sd = sdecs + tk * SSTR;
        const int t0 = th * 3;
#pragma unroll
        for (int t = 0; t < 3; ++t) {
            int tt = t0 + t;
            float s0 = sd[tt * 7 + n0], s1 = sd[tt * 7 + n1], s2 = sd[tt * 7 + n2];
            float pb = g[tt] * ginv
                     * (d0 * s0 + (1.0f - d0) * (1.0f - s0))
                     * (d1 * s1 + (1.0f - d1) * (1.0f - s1))
                     * (d2 * s2 + (1.0f - d2) * (1.0f - s2));
            rt[tk][tt * 8 + l] = f2b(pb);
        }
    }
    __syncthreads();

    // ---------------- phase 2: out GEMM ---------------------------------
    // Each wave: 384 cols = 6 groups of 64 cols (4 MFMA tiles each).
    // Group starts are multiples of 64 -> never straddle a head boundary.
    // Per group: 12 lot loads -> 12 MFMA -> acc to wave-private LDS
    // (in-order DS, no barrier) -> 4 plain float4 stores, each covering
    // 8 full 128-B lines.
    {
        short8 a[3];
#pragma unroll
        for (int kk = 0; kk < 3; ++kk)
            a[kk] = *(const short8*)(&rt[lrow][quad * 8 + kk * 32]);

        float* wb = &stg[wave][0];

#pragma unroll
        for (int g = 0; g < 6; ++g) {
            const int s    = wave * 384 + g * 64;
            const int h    = s >> 10;
            const int dcol = s & 1023;
            const ushort* bp0 = lot + (size_t)h * LOT_H
                              + (size_t)(dcol + lrow) * NJ + quad * 8;

            floatx4 c0 = (floatx4)(0.0f), c1 = (floatx4)(0.0f);
            floatx4 c2 = (floatx4)(0.0f), c3 = (floatx4)(0.0f);
#pragma unroll
            for (int kk = 0; kk < 3; ++kk) {
                short8 b0 = *(const short8*)(bp0 + 0 * 16 * NJ + kk * 32);
                short8 b1 = *(const short8*)(bp0 + 1 * 16 * NJ + kk * 32);
                short8 b2 = *(const short8*)(bp0 + 2 * 16 * NJ + kk * 32);
                short8 b3 = *(const short8*)(bp0 + 3 * 16 * NJ + kk * 32);
                c0 = __builtin_amdgcn_mfma_f32_16x16x32_bf16(a[kk], b0, c0, 0, 0, 0);
                c1 = __builtin_amdgcn_mfma_f32_16x16x32_bf16(a[kk], b1, c1, 0, 0, 0);
                c2 = __builtin_amdgcn_mfma_f32_16x16x32_bf16(a[kk], b2, c2, 0, 0, 0);
                c3 = __builtin_amdgcn_mfma_f32_16x16x32_bf16(a[kk], b3, c3, 0, 0, 0);
            }
            // stage: row = token (quad*4+r), col = tile*16 + lrow
#pragma unroll
            for (int r = 0; r < 4; ++r) {
                wb[(quad * 4 + r) * STG +  0 + lrow] = c0[r];
                wb[(quad * 4 + r) * STG + 16 + lrow] = c1[r];
                wb[(quad * 4 + r) * STG + 32 + lrow] = c2[r];
                wb[(quad * 4 + r) * STG + 48 + lrow] = c3[r];
            }
            // store: 4 instrs, each 8 rows x 32 consecutive floats (128B lines)
#pragma unroll
            for (int i = 0; i < 4; ++i) {
                const int row  = (i & 1) * 8 + (lane >> 3);
                const int colh = (i >> 1) * 32 + (lane & 7) * 4;
                floatx4 v = *(const floatx4*)(wb + row * STG + colh);
                *(floatx4*)(out + ((size_t)h * NTOK + tb + row) * DOUT
                            + dcol + colh) = v;
            }
        }
    }
}

// ---------------------------------------------------------------------------
extern "C" void kernel_launch(void* const* d_in, const int* in_sizes, int n_in,
                              void* d_out, int out_size, void* d_ws, size_t ws_size,
                              hipStream_t stream) {
    const float* x   = (const float*)d_in[0];
    const float* dw  = (const float*)d_in[1];
    const float* db  = (const float*)d_in[2];
    const float* ntl = (const float*)d_in[3];
    const float* gw  = (const float*)d_in[4];
    const float* gb  = (const float*)d_in[5];
    const float* lo  = (const float*)d_in[6];
    const int*   pi  = (const int*)d_in[7];
    const float* pd  = (const float*)d_in[8];
    float* out = (float*)d_out;

    ushort* lot  = (ushort*)d_ws;                 // 3*98304*2 = 0.59 MB
    ushort* wcat = lot + (size_t)3 * LOT_H;       // 96*1024*2 = 0.20 MB

    k_prep<<<dim3((3 * LOT_H + NJ * DIN) / 256), dim3(256), 0, stream>>>(lo, dw, gw, lot, wcat);
    k_fused<<<dim3(NTOK / TOKPB), dim3(512), 0, stream>>>(x, wcat, db, ntl, gb, pi, pd, lot, out);
}

// Round 8
// 170.833 us; speedup vs baseline: 1.0437x; 1.0413x over previous
//
#include <hip/hip_runtime.h>

typedef __attribute__((ext_vector_type(8))) short short8;
typedef __attribute__((ext_vector_type(4))) float floatx4;
typedef unsigned int uint;
typedef unsigned short ushort;
typedef __attribute__((ext_vector_type(4))) uint uintx4;

#define NTOK   8192
#define DIN    1024
#define DOUT   1024
#define NJ     96        // 84 decision nodes (12 trees x 7) + 12 gates
#define TOKPB  16        // tokens per block -> 512 blocks
#define DSTR   97        // decis LDS row stride (f32)
#define SSTR   85        // sdec LDS row stride (f32)
#define RSTR   104       // routed LDS tile row stride (bf16)
#define LOT_H  (DOUT * NJ)

static __device__ inline ushort f2b(float f) {
    uint u = __builtin_bit_cast(uint, f);
    u = u + 0x7fffu + ((u >> 16) & 1u);   // RNE
    return (ushort)(u >> 16);
}
static __device__ inline uint pack2(float a, float b) {
    return (uint)f2b(a) | ((uint)f2b(b) << 16);
}

// ---------------------------------------------------------------------------
// k_prep: f32 -> bf16.
//   lo [3][96][1024] -> lot BLOCKED: [3][64 dt][3 kk][16 dr][32 kr]
//     (so one phase-2 fragment-load instruction = 1024 CONTIGUOUS bytes,
//      vs 16 scattered 64-B segments with the old [d][k] layout)
//   dw[84][1024] ++ gw[12][1024] -> wcat[96][1024].
// ---------------------------------------------------------------------------
__global__ __launch_bounds__(256) void k_prep(const float* __restrict__ lo,
                                              const float* __restrict__ dw,
                                              const float* __restrict__ gw,
                                              ushort* __restrict__ lot,
                                              ushort* __restrict__ wcat) {
    int i = blockIdx.x * 256 + threadIdx.x;
    if (i < 3 * LOT_H) {
        int h = i / LOT_H;
        int rem = i - h * LOT_H;
        int k = rem >> 10;        // 0..95
        int d = rem & 1023;       // 0..1023
        int off = (((d >> 4) * 3 + (k >> 5)) << 9) + ((d & 15) << 5) + (k & 31);
        lot[h * LOT_H + off] = f2b(lo[i]);
    } else {
        int j = i - 3 * LOT_H;
        int r = j >> 10, c = j & 1023;
        float v = (r < 84) ? dw[r * DIN + c] : gw[(r - 84) * DIN + c];
        wcat[j] = f2b(v);
    }
}

// ---------------------------------------------------------------------------
// k_fused: 16 tokens/block, 512 blocks, 256 threads (4 waves).
// R7 lesson: store amplification fixed but dur invariant -> limiter is
// address-divergence + store shape.  This version:
//   phase 1 (wave0{0,4} wave1{1,5} wave2{2} wave3{3} N-tiles): barrier-free
//     decisions+gates GEMM; A per-lane from global x (f32->bf16 pack),
//     B from wcat (L2-hot).
//   epilogue: acc -> decis -> sigmoid -> routing -> rt tile (3 barriers).
//   phase 2: out GEMM with SWAPPED MFMA operands: c = mfma(lot_frag,
//     rt_frag, c) puts 4 consecutive d in each lane -> one float4 plain
//     store per tile (16 rows x 64-B full sectors per instruction).
//     lot is blocked so each fragment load is 1024 contiguous bytes.
//     No LDS staging, no scalar stores.  Double-buffered lot frags.
// ---------------------------------------------------------------------------
__global__ __launch_bounds__(256, 2) void k_fused(
    const float* __restrict__ x,     // [8192][1024] f32
    const ushort* __restrict__ wcat, // [96][1024] bf16
    const float* __restrict__ db,    // [84]
    const float* __restrict__ ntl,   // [84]
    const float* __restrict__ gb,    // [12]
    const int*   __restrict__ pi,    // [8][3]
    const float* __restrict__ pd,    // [8][3]
    const ushort* __restrict__ lot,  // [3][64][3][16][32] bf16 (blocked)
    float* __restrict__ out)         // [3][8192][1024] f32
{
    __shared__ float decis[TOKPB * DSTR];
    __shared__ float sdecs[TOKPB * SSTR];
    __shared__ __attribute__((aligned(16))) ushort rt[TOKPB][RSTR];
    __shared__ float invt[84];
    __shared__ float biasf[96];
    __shared__ int   pis[24];
    __shared__ float pds[24];

    const int tid = threadIdx.x;
    const int tb  = blockIdx.x * TOKPB;

    if (tid < 84) {
        float z = ntl[tid] + 0.5413f;
        float sp = (z > 20.0f) ? z : log1pf(__expf(z));   // softplus
        invt[tid]  = 1.0f / sp;
        biasf[tid] = db[tid];
    } else if (tid < 96) {
        biasf[tid] = gb[tid - 84];
    } else if (tid < 120) {
        pis[tid - 96] = pi[tid - 96];
    } else if (tid < 144) {
        pds[tid - 120] = pd[tid - 120];
    }

    const int wave = tid >> 6, lane = tid & 63;
    const int lrow = lane & 15, quad = lane >> 4;

    // ---------------- phase 1: N-tile ownership --------------------------
    const int nt0 = wave;
    const bool two = (wave < 2);
    const int nt1 = wave + 4;

    floatx4 acc0 = (floatx4)(0.0f), acc1 = (floatx4)(0.0f);

    const float*  xr = x    + (size_t)(tb + lrow) * DIN + quad * 8;
    const ushort* w0 = wcat + (size_t)(nt0 * 16 + lrow) * DIN + quad * 8;
    const ushort* w1 = wcat + (size_t)(nt1 * 16 + lrow) * DIN + quad * 8;

#pragma unroll
    for (int kc = 0; kc < 8; ++kc) {
        short8 a[4];
#pragma unroll
        for (int kt = 0; kt < 4; ++kt) {
            floatx4 u = *(const floatx4*)(xr + kc * 128 + kt * 32);
            floatx4 v = *(const floatx4*)(xr + kc * 128 + kt * 32 + 4);
            union { short8 s; uint w[4]; } pk;
            pk.w[0] = pack2(u[0], u[1]);
            pk.w[1] = pack2(u[2], u[3]);
            pk.w[2] = pack2(v[0], v[1]);
            pk.w[3] = pack2(v[2], v[3]);
            a[kt] = pk.s;
        }
#pragma unroll
        for (int kt = 0; kt < 4; ++kt) {
            short8 b0 = *(const short8*)(w0 + kc * 128 + kt * 32);
            acc0 = __builtin_amdgcn_mfma_f32_16x16x32_bf16(a[kt], b0, acc0, 0, 0, 0);
        }
        if (two) {
#pragma unroll
            for (int kt = 0; kt < 4; ++kt) {
                short8 b1 = *(const short8*)(w1 + kc * 128 + kt * 32);
                acc1 = __builtin_amdgcn_mfma_f32_16x16x32_bf16(a[kt], b1, acc1, 0, 0, 0);
            }
        }
    }

    // ---------------- epilogue: routing ---------------------------------
    // C/D: col = lane&15 (j within 16-tile), row = quad*4+reg (token)
#pragma unroll
    for (int r = 0; r < 4; ++r)
        decis[(quad * 4 + r) * DSTR + nt0 * 16 + lrow] = acc0[r];
    if (two) {
#pragma unroll
        for (int r = 0; r < 4; ++r)
            decis[(quad * 4 + r) * DSTR + nt1 * 16 + lrow] = acc1[r];
    }
    __syncthreads();

    // stage 1: sigmoid over 16 tokens x 84 nodes = 1344
#pragma unroll
    for (int i = 0; i < 6; ++i) {
        int idx = tid + 256 * i;
        if (idx < TOKPB * 84) {
            int tk = idx / 84, nd = idx - tk * 84;
            float dv = (decis[tk * DSTR + nd] + biasf[nd]) * invt[nd];
            sdecs[tk * SSTR + nd] = 1.0f / (1.0f + __expf(-dv));
        }
    }
    __syncthreads();

    // stage 2: 256 threads = 16 tokens x 8 leaves x 2 tree-halves -> rt
    {
        const int tk = tid >> 4, l = (tid >> 1) & 7, th = tid & 1;
        float g[12], gm = -1e30f;
#pragma unroll
        for (int tt = 0; tt < 12; ++tt) {
            g[tt] = decis[tk * DSTR + 84 + tt] + biasf[84 + tt];
            gm = fmaxf(gm, g[tt]);
        }
        float gs = 0.0f;
#pragma unroll
        for (int tt = 0; tt < 12; ++tt) { g[tt] = __expf(g[tt] - gm); gs += g[tt]; }
        float ginv = 1.0f / gs;

        const int   n0 = pis[l * 3 + 0], n1 = pis[l * 3 + 1], n2 = pis[l * 3 + 2];
        const float d0 = pds[l * 3 + 0], d1 = pds[l * 3 + 1], d2 = pds[l * 3 + 2];
        const float* sd = sdecs + tk * SSTR;
        const int t0 = th * 6;
#pragma unroll
        for (int t = 0; t < 6; ++t) {
            int tt = t0 + t;
            float s0 = sd[tt * 7 + n0], s1 = sd[tt * 7 + n1], s2 = sd[tt * 7 + n2];
            float pb = g[tt] * ginv
                     * (d0 * s0 + (1.0f - d0) * (1.0f - s0))
                     * (d1 * s1 + (1.0f - d1) * (1.0f - s1))
                     * (d2 * s2 + (1.0f - d2) * (1.0f - s2));
            rt[tk][tt * 8 + l] = f2b(pb);
        }
    }
    __syncthreads();

    // ---------------- phase 2: out GEMM (swapped operands) ---------------
    // Each wave: 768 cols = 48 16-col d-tiles.  Per tile:
    //   lot frag  ("A", m = d): 3 x short8, CONTIGUOUS 1KB per instr
    //   rt  frag  ("B", n = token): 3 x short8 from LDS (once)
    //   c = mfma(lot, rt, c) -> lane holds out[d = dt*16+quad*4 .. +3]
    //                                   [token = tb+lrow]  -> one float4 store
    {
        short8 ar[3];
#pragma unroll
        for (int kk = 0; kk < 3; ++kk)
            ar[kk] = *(const short8*)(&rt[lrow][quad * 8 + kk * 32]);

        const int tilebase = wave * 768;   // in columns
        short8 bl[2][3];
#define LOADT(B, T) do { \
        int c_ = tilebase + (T) * 16; \
        int h_ = c_ >> 10; \
        int dt_ = (c_ & 1023) >> 4; \
        const ushort* p_ = lot + (size_t)h_ * LOT_H + ((size_t)(dt_ * 3) << 9) \
                         + (lrow << 5) + quad * 8; \
        bl[B][0] = *(const short8*)(p_); \
        bl[B][1] = *(const short8*)(p_ + 512); \
        bl[B][2] = *(const short8*)(p_ + 1024); \
    } while (0)

        LOADT(0, 0);
#pragma unroll
        for (int t = 0; t < 48; ++t) {
            const int cur = t & 1;
            if (t < 47) LOADT(cur ^ 1, t + 1);
            floatx4 c = (floatx4)(0.0f);
#pragma unroll
            for (int kk = 0; kk < 3; ++kk)
                c = __builtin_amdgcn_mfma_f32_16x16x32_bf16(bl[cur][kk], ar[kk], c, 0, 0, 0);
            const int col = tilebase + t * 16;
            const int h = col >> 10;
            const int d = (col & 1023) + quad * 4;
            *(floatx4*)(out + ((size_t)h * NTOK + tb + lrow) * DOUT + d) = c;
        }
#undef LOADT
    }
}

// ---------------------------------------------------------------------------
extern "C" void kernel_launch(void* const* d_in, const int* in_sizes, int n_in,
                              void* d_out, int out_size, void* d_ws, size_t ws_size,
                              hipStream_t stream) {
    const float* x   = (const float*)d_in[0];
    const float* dw  = (const float*)d_in[1];
    const float* db  = (const float*)d_in[2];
    const float* ntl = (const float*)d_in[3];
    const float* gw  = (const float*)d_in[4];
    const float* gb  = (const float*)d_in[5];
    const float* lo  = (const float*)d_in[6];
    const int*   pi  = (const int*)d_in[7];
    const float* pd  = (const float*)d_in[8];
    float* out = (float*)d_out;

    ushort* lot  = (ushort*)d_ws;                 // 3*98304*2 = 0.59 MB
    ushort* wcat = lot + (size_t)3 * LOT_H;       // 96*1024*2 = 0.20 MB

    k_prep<<<dim3((3 * LOT_H + NJ * DIN) / 256), dim3(256), 0, stream>>>(lo, dw, gw, lot, wcat);
    k_fused<<<dim3(NTOK / TOKPB), dim3(256), 0, stream>>>(x, wcat, db, ntl, gb, pi, pd, lot, out);
}

// Round 11
// 157.885 us; speedup vs baseline: 1.1293x; 1.0820x over previous
//
#include <hip/hip_runtime.h>

typedef __attribute__((ext_vector_type(8))) short short8;
typedef __attribute__((ext_vector_type(4))) float floatx4;
typedef unsigned int uint;
typedef unsigned short ushort;
typedef __attribute__((ext_vector_type(4))) uint uintx4;

#define NTOK   8192
#define DIN    1024
#define DOUT   1024
#define NJ     96        // 84 decision nodes (12 trees x 7) + 12 gates
#define TOKPB  16        // tokens per block -> 512 blocks (2/CU)
#define XSTR   136       // LDS row stride (bf16 elems) for x/w tiles
#define DSTR   97        // decis LDS row stride (f32)
#define SSTR   85        // sdec LDS row stride (f32)
#define RSTR   104       // routed LDS tile row stride (bf16)
#define LOT_H  (DOUT * NJ)

static __device__ inline ushort f2b(float f) {
    uint u = __builtin_bit_cast(uint, f);
    u = u + 0x7fffu + ((u >> 16) & 1u);   // RNE
    return (ushort)(u >> 16);
}
static __device__ inline uint pack2(float a, float b) {
    return (uint)f2b(a) | ((uint)f2b(b) << 16);
}

// ---------------------------------------------------------------------------
// k_prep: f32 -> bf16.
//   lo [3][96][1024] -> lot BLOCKED: [3][64 dt][3 kk][16 dr][32 kr]
//     (one phase-2 fragment load = 1024 CONTIGUOUS bytes)
//   dw[84][1024] ++ gw[12][1024] -> wcat[96][1024].
// ---------------------------------------------------------------------------
__global__ __launch_bounds__(256) void k_prep(const float* __restrict__ lo,
                                              const float* __restrict__ dw,
                                              const float* __restrict__ gw,
                                              ushort* __restrict__ lot,
                                              ushort* __restrict__ wcat) {
    int i = blockIdx.x * 256 + threadIdx.x;
    if (i < 3 * LOT_H) {
        int h = i / LOT_H;
        int rem = i - h * LOT_H;
        int k = rem >> 10;        // 0..95
        int d = rem & 1023;       // 0..1023
        int off = (((d >> 4) * 3 + (k >> 5)) << 9) + ((d & 15) << 5) + (k & 31);
        lot[h * LOT_H + off] = f2b(lo[i]);
    } else {
        int j = i - 3 * LOT_H;
        int r = j >> 10, c = j & 1023;
        float v = (r < 84) ? dw[r * DIN + c] : gw[(r - 84) * DIN + c];
        wcat[j] = f2b(v);
    }
}

// ---------------------------------------------------------------------------
// k_fused (16 tokens/block, 512 blocks, 256 threads, 2 blocks/CU):
//   phase 1 (R3-verbatim, the ~32us base): LDS-staged decisions+gates GEMM.
//     Coalesced float4 x loads -> bf16 pack -> LDS; register double-buffer;
//     2-barrier K-loop.  (R5-R8 lesson: per-lane "barrier-free" global-x
//     fragments are 16-line divergent per instruction -> 2x regression.)
//   epilogue: acc -> decis -> sigmoid -> routing -> rt tile.
//   phase 2 (pieces proven in R7/R8): swapped-operand MFMA
//     c = mfma(lot_frag, rt_frag, c) -> lane holds 4 consecutive d for one
//     token -> ONE float4 plain store per tile (full 64B sectors).
//     Blocked lot -> 3 x 1KB contiguous loads per tile.  Triple-buffered
//     prefetch at DISTANCE 2 GROUPS so in-order vmcnt retirement of the
//     interleaved stores never blocks the loads' consumers (R8 lesson).
// ---------------------------------------------------------------------------
__global__ __launch_bounds__(256, 2) void k_fused(
    const float* __restrict__ x,     // [8192][1024] f32
    const ushort* __restrict__ wcat, // [96][1024] bf16
    const float* __restrict__ db,    // [84]
    const float* __restrict__ ntl,   // [84]
    const float* __restrict__ gb,    // [12]
    const int*   __restrict__ pi,    // [8][3]
    const float* __restrict__ pd,    // [8][3]
    const ushort* __restrict__ lot,  // [3][64][3][16][32] bf16 (blocked)
    float* __restrict__ out)         // [3][8192][1024] f32
{
    __shared__ __attribute__((aligned(16))) char smem[30464];
    __shared__ __attribute__((aligned(16))) ushort rt[TOKPB][RSTR];
    __shared__ float invt[84];
    __shared__ float biasf[96];
    __shared__ int   pis[24];
    __shared__ float pds[24];

    ushort* xl = (ushort*)smem;                        // [16][XSTR] bf16
    ushort* wl = (ushort*)(smem + TOKPB * XSTR * 2);   // [96][XSTR] bf16
    float*  decis = (float*)smem;                      // [16][DSTR] f32 (reuse)
    float*  sdecs = (float*)(smem + TOKPB * DSTR * 4); // [16][SSTR] f32

    const int tid = threadIdx.x;
    const int tb  = blockIdx.x * TOKPB;

    if (tid < 84) {
        float z = ntl[tid] + 0.5413f;
        float sp = (z > 20.0f) ? z : log1pf(__expf(z));   // softplus
        invt[tid]  = 1.0f / sp;
        biasf[tid] = db[tid];
    } else if (tid < 96) {
        biasf[tid] = gb[tid - 84];
    } else if (tid < 120) {
        pis[tid - 96] = pi[tid - 96];
    } else if (tid < 144) {
        pds[tid - 120] = pd[tid - 120];
    }

    const int wave = tid >> 6, lane = tid & 63;
    const int lrow = lane & 15, quad = lane >> 4;

    // phase-1 N-tile ownership: wave0 {0,4}, wave1 {1,5}, wave2 {2}, wave3 {3}
    const int nt0 = wave;
    const bool two = (wave < 2);
    const int nt1 = wave + 4;

    floatx4 acc0 = (floatx4)(0.0f), acc1 = (floatx4)(0.0f);

    // register double-buffers for staged tiles
    floatx4 xv[2][2];
    uintx4  wv[2][6];

#define LOADX(B, KC) do { \
    _Pragma("unroll") for (int i_ = 0; i_ < 2; ++i_) { \
        int idx_ = tid + 256 * i_; \
        int r_ = idx_ >> 5, c_ = idx_ & 31; \
        xv[B][i_] = __builtin_nontemporal_load( \
            (const floatx4*)(x + (size_t)(tb + r_) * DIN + (KC) * 128 + c_ * 4)); \
    } } while (0)

#define LOADW(B, KC) do { \
    _Pragma("unroll") for (int i_ = 0; i_ < 6; ++i_) { \
        int idx_ = tid + 256 * i_; \
        int r_ = idx_ >> 4, c_ = idx_ & 15; \
        wv[B][i_] = *(const uintx4*)(wcat + r_ * DIN + (KC) * 128 + c_ * 8); \
    } } while (0)

#define STAGE(B) do { \
    _Pragma("unroll") for (int i_ = 0; i_ < 2; ++i_) { \
        int idx_ = tid + 256 * i_; \
        int r_ = idx_ >> 5, c_ = idx_ & 31; \
        uint2 p_; \
        p_.x = pack2(xv[B][i_][0], xv[B][i_][1]); \
        p_.y = pack2(xv[B][i_][2], xv[B][i_][3]); \
        *(uint2*)(xl + r_ * XSTR + c_ * 4) = p_; \
    } \
    _Pragma("unroll") for (int i_ = 0; i_ < 6; ++i_) { \
        int idx_ = tid + 256 * i_; \
        int r_ = idx_ >> 4, c_ = idx_ & 15; \
        *(uintx4*)(wl + r_ * XSTR + c_ * 8) = wv[B][i_]; \
    } } while (0)

    LOADX(0, 0);
    LOADW(0, 0);

#pragma unroll
    for (int kc = 0; kc < 8; ++kc) {
        const int cur = kc & 1, nxt = cur ^ 1;
        __syncthreads();            // previous iter's ds_reads complete
        STAGE(cur);
        __syncthreads();
        if (kc < 7) {               // issue next tile's loads early
            LOADX(nxt, kc + 1);
            LOADW(nxt, kc + 1);
        }

        short8 a[4];
#pragma unroll
        for (int kt = 0; kt < 4; ++kt)
            a[kt] = *(const short8*)(xl + lrow * XSTR + kt * 32 + quad * 8);
#pragma unroll
        for (int kt = 0; kt < 4; ++kt) {
            short8 b0 = *(const short8*)(wl + (nt0 * 16 + lrow) * XSTR + kt * 32 + quad * 8);
            acc0 = __builtin_amdgcn_mfma_f32_16x16x32_bf16(a[kt], b0, acc0, 0, 0, 0);
        }
        if (two) {
#pragma unroll
            for (int kt = 0; kt < 4; ++kt) {
                short8 b1 = *(const short8*)(wl + (nt1 * 16 + lrow) * XSTR + kt * 32 + quad * 8);
                acc1 = __builtin_amdgcn_mfma_f32_16x16x32_bf16(a[kt], b1, acc1, 0, 0, 0);
            }
        }
    }
#undef LOADX
#undef LOADW
#undef STAGE

    __syncthreads();
    // C/D: col = lane&15 (j within 16-tile), row = quad*4+reg (token)
#pragma unroll
    for (int r = 0; r < 4; ++r)
        decis[(quad * 4 + r) * DSTR + nt0 * 16 + lrow] = acc0[r];
    if (two) {
#pragma unroll
        for (int r = 0; r < 4; ++r)
            decis[(quad * 4 + r) * DSTR + nt1 * 16 + lrow] = acc1[r];
    }
    __syncthreads();

    // stage 1: sigmoid over 16 tokens x 84 nodes = 1344
#pragma unroll
    for (int i = 0; i < 6; ++i) {
        int idx = tid + 256 * i;
        if (idx < TOKPB * 84) {
            int tk = idx / 84, nd = idx - tk * 84;
            float dv = (decis[tk * DSTR + nd] + biasf[nd]) * invt[nd];
            sdecs[tk * SSTR + nd] = 1.0f / (1.0f + __expf(-dv));
        }
    }
    __syncthreads();

    // stage 2: 256 threads = 16 tokens x 8 leaves x 2 tree-halves -> rt
    {
        const int tk = tid >> 4, l = (tid >> 1) & 7, th = tid & 1;
        float g[12], gm = -1e30f;
#pragma unroll
        for (int tt = 0; tt < 12; ++tt) {
            g[tt] = decis[tk * DSTR + 84 + tt] + biasf[84 + tt];
            gm = fmaxf(gm, g[tt]);
        }
        float gs = 0.0f;
#pragma unroll
        for (int tt = 0; tt < 12; ++tt) { g[tt] = __expf(g[tt] - gm); gs += g[tt]; }
        float ginv = 1.0f / gs;

        const int   n0 = pis[l * 3 + 0], n1 = pis[l * 3 + 1], n2 = pis[l * 3 + 2];
        const float d0 = pds[l * 3 + 0], d1 = pds[l * 3 + 1], d2 = pds[l * 3 + 2];
        const float* sd = sdecs + tk * SSTR;
        const int t0 = th * 6;
#pragma unroll
        for (int t = 0; t < 6; ++t) {
            int tt = t0 + t;
            float s0 = sd[tt * 7 + n0], s1 = sd[tt * 7 + n1], s2 = sd[tt * 7 + n2];
            float pb = g[tt] * ginv
                     * (d0 * s0 + (1.0f - d0) * (1.0f - s0))
                     * (d1 * s1 + (1.0f - d1) * (1.0f - s1))
                     * (d2 * s2 + (1.0f - d2) * (1.0f - s2));
            rt[tk][tt * 8 + l] = f2b(pb);
        }
    }
    __syncthreads();

    // ---------------- phase 2: out GEMM (swapped operands) ---------------
    // Each wave: 48 d-tiles (768 cols).  Per tile:
    //   A = lot frag (m = d): 3 x short8, contiguous 1KB per load instr
    //   B = rt frag  (n = token): 3 x short8 from LDS (read once)
    //   c = mfma(A,B,c) -> lane: token = lane&15, d = dt*16 + quad*4 + reg
    //   -> one float4 plain store (full 64-B sector, 16 rows/instr).
    // Triple buffer, 2-tile groups, prefetch distance 2 groups: loads for
    // group g+2 are issued before group g's stores, so in-order vmcnt
    // retirement (stores block younger loads' visibility) has 1-group slack.
    {
        short8 ar[3];
#pragma unroll
        for (int kk = 0; kk < 3; ++kk)
            ar[kk] = *(const short8*)(&rt[lrow][quad * 8 + kk * 32]);

        const int tilebase = wave * 48;   // tile index; 64 tiles per head
        short8 bb[3][6];
#define LOADB(B, G) do { \
    _Pragma("unroll") for (int q_ = 0; q_ < 2; ++q_) { \
        int t_ = tilebase + (G) * 2 + q_; \
        int h_ = t_ >> 6; \
        int dt_ = t_ & 63; \
        const ushort* p_ = lot + (size_t)h_ * LOT_H + dt_ * 1536 \
                         + (lrow << 5) + quad * 8; \
        bb[B][q_ * 3 + 0] = *(const short8*)(p_); \
        bb[B][q_ * 3 + 1] = *(const short8*)(p_ + 512); \
        bb[B][q_ * 3 + 2] = *(const short8*)(p_ + 1024); \
    } } while (0)

        LOADB(0, 0);
        LOADB(1, 1);
#pragma unroll
        for (int g = 0; g < 24; ++g) {
            const int cur = g % 3;
            if (g < 22) LOADB((g + 2) % 3, g + 2);
#pragma unroll
            for (int q = 0; q < 2; ++q) {
                floatx4 c = (floatx4)(0.0f);
#pragma unroll
                for (int kk = 0; kk < 3; ++kk)
                    c = __builtin_amdgcn_mfma_f32_16x16x32_bf16(bb[cur][q * 3 + kk], ar[kk], c, 0, 0, 0);
                const int t = tilebase + g * 2 + q;
                const int h = t >> 6;
                const int d = (t & 63) * 16 + quad * 4;
                *(floatx4*)(out + ((size_t)h * NTOK + tb + lrow) * DOUT + d) = c;
            }
        }
#undef LOADB
    }
}

// ---------------------------------------------------------------------------
extern "C" void kernel_launch(void* const* d_in, const int* in_sizes, int n_in,
                              void* d_out, int out_size, void* d_ws, size_t ws_size,
                              hipStream_t stream) {
    const float* x   = (const float*)d_in[0];
    const float* dw  = (const float*)d_in[1];
    const float* db  = (const float*)d_in[2];
    const float* ntl = (const float*)d_in[3];
    const float* gw  = (const float*)d_in[4];
    const float* gb  = (const float*)d_in[5];
    const float* lo  = (const float*)d_in[6];
    const int*   pi  = (const int*)d_in[7];
    const float* pd  = (const float*)d_in[8];
    float* out = (float*)d_out;

    ushort* lot  = (ushort*)d_ws;                 // 3*98304*2 = 0.59 MB
    ushort* wcat = lot + (size_t)3 * LOT_H;       // 96*1024*2 = 0.20 MB

    k_prep<<<dim3((3 * LOT_H + NJ * DIN) / 256), dim3(256), 0, stream>>>(lo, dw, gw, lot, wcat);
    k_fused<<<dim3(NTOK / TOKPB), dim3(256), 0, stream>>>(x, wcat, db, ntl, gb, pi, pd, lot, out);
}